// Round 7
// baseline (487.850 us; speedup 1.0000x reference)
//
#include <hip/hip_runtime.h>

#define NV   100000
#define NE   50000
#define NNZ  3200000
#define KIN  256
#define KOUT 64

#define NB    400                  // partition/hist blocks (NNZ = 400*8000 exactly)
#define CHUNK (NNZ / NB)           // 8000
#define NBE   782                  // ceil(NE/64) edge buckets
#define NBV   1563                 // ceil(NV/64) vertex buckets
#define NBINS (NBE + NBV)          // 2345
#define LSCAN (NBINS * NB)         // 938000
#define NBLK_SCAN ((LSCAN + 1023) / 1024)   // 917 (must stay <= 1024 for k_scan2)

// ---------------------------------------------------------------------------
// Kernel 1: Xp[r][o] = sum_k X[r][k] * W[o][k]
// Zero-LDS design: lane = output channel o (KOUT == wave width).
//   - W[o][k0..k0+63] lives in 64 VGPRs per K-chunk (per-lane private row;
//     W is already o-major so loads need no transpose).
//   - X rows are wave-uniform: readfirstlane'd row pointers -> scalar (SMEM)
//     loads, keeping the DS pipe at ZERO and VALU = pure FMA.
//   - 8 rows/wave, 8-way independent FMA chains per k-quad.
// Grid: 3125 blocks x 32 rows = 100000 exactly (no tail guard needed).
// ---------------------------------------------------------------------------
__global__ __launch_bounds__(256) void k_project(const float* __restrict__ X,
                                                 const float* __restrict__ W,
                                                 float* __restrict__ Xp) {
    const int tid = threadIdx.x;
    const int o   = tid & 63;            // lane = output channel
    const int wv  = tid >> 6;            // wave id 0..3
    const int rbase = blockIdx.x * 32 + wv * 8;

    const float* xrow[8];
#pragma unroll
    for (int r = 0; r < 8; ++r) {
        const int row = __builtin_amdgcn_readfirstlane(rbase + r);
        xrow[r] = X + (size_t)row * KIN;
    }
    const float* wrow = W + (size_t)o * KIN;

    float acc[8];
#pragma unroll
    for (int r = 0; r < 8; ++r) acc[r] = 0.0f;

    for (int kc = 0; kc < KIN / 64; ++kc) {
        float4 w4[16];                   // this chunk's 64 W values (per-lane)
#pragma unroll
        for (int q = 0; q < 16; ++q)
            w4[q] = *(const float4*)(wrow + kc * 64 + 4 * q);

#pragma unroll
        for (int q = 0; q < 16; ++q) {
            float4 xq[8];                // wave-uniform -> SGPR candidates
#pragma unroll
            for (int r = 0; r < 8; ++r)
                xq[r] = *(const float4*)(xrow[r] + kc * 64 + 4 * q);
#pragma unroll
            for (int r = 0; r < 8; ++r) {
                acc[r] = fmaf(xq[r].x, w4[q].x, acc[r]);
                acc[r] = fmaf(xq[r].y, w4[q].y, acc[r]);
                acc[r] = fmaf(xq[r].z, w4[q].z, acc[r]);
                acc[r] = fmaf(xq[r].w, w4[q].w, acc[r]);
            }
        }
    }

#pragma unroll
    for (int r = 0; r < 8; ++r)
        Xp[(size_t)(rbase + r) * KOUT + o] = acc[r];   // coalesced 256B/wave
}

// ---------------------------------------------------------------------------
// Per-block LDS histogram of BOTH bucket keys -> count matrix
// mat[bucket * NB + block]; E buckets [0,NBE), V buckets [NBE, NBINS)
// ---------------------------------------------------------------------------
__global__ __launch_bounds__(256) void k_hist(const int* __restrict__ v_idx,
                                              const int* __restrict__ e_idx,
                                              int* __restrict__ mat) {
    __shared__ int h[NBINS];
    const int b = blockIdx.x, tid = threadIdx.x;
    for (int i = tid; i < NBINS; i += 256) h[i] = 0;
    __syncthreads();
    const int base = b * CHUNK;
    for (int i = tid; i < CHUNK; i += 256) {
        atomicAdd(&h[e_idx[base + i] >> 6], 1);
        atomicAdd(&h[NBE + (v_idx[base + i] >> 6)], 1);
    }
    __syncthreads();
    for (int j = tid; j < NBINS; j += 256) mat[j * NB + b] = h[j];
}

// ---------------------------------------------------------------------------
// 3-kernel exclusive scan of mat[LSCAN]
// ---------------------------------------------------------------------------
__global__ __launch_bounds__(1024) void k_scan1(int* __restrict__ mat,
                                                int* __restrict__ bsum) {
    __shared__ int buf[1024];
    const int tid = threadIdx.x;
    const int i = blockIdx.x * 1024 + tid;
    const int v = (i < LSCAN) ? mat[i] : 0;
    buf[tid] = v;
    __syncthreads();
    for (int d = 1; d < 1024; d <<= 1) {
        int t = (tid >= d) ? buf[tid - d] : 0;
        __syncthreads();
        buf[tid] += t;
        __syncthreads();
    }
    if (i < LSCAN) mat[i] = buf[tid] - v;          // local exclusive
    if (tid == 1023) bsum[blockIdx.x] = buf[1023]; // block total
}

__global__ __launch_bounds__(1024) void k_scan2(int* __restrict__ bsum) {
    __shared__ int buf[1024];
    const int tid = threadIdx.x;
    const int v = (tid < NBLK_SCAN) ? bsum[tid] : 0;
    buf[tid] = v;
    __syncthreads();
    for (int d = 1; d < 1024; d <<= 1) {
        int t = (tid >= d) ? buf[tid - d] : 0;
        __syncthreads();
        buf[tid] += t;
        __syncthreads();
    }
    if (tid < NBLK_SCAN) bsum[tid] = buf[tid] - v; // exclusive block offsets
}

__global__ __launch_bounds__(1024) void k_scan3(int* __restrict__ mat,
                                                const int* __restrict__ bsum) {
    const int i = blockIdx.x * 1024 + threadIdx.x;
    if (i < LSCAN) mat[i] += bsum[blockIdx.x];
}

// ---------------------------------------------------------------------------
// Partition: cursors come from scanned matrix (LDS copies), no global atomics.
// part[p] = val | (localKey << 17)   (val < 2^17, localKey = key & 63)
// ---------------------------------------------------------------------------
__global__ __launch_bounds__(256) void k_partition(const int* __restrict__ key,
                                                   const int* __restrict__ val,
                                                   const int* __restrict__ mat,
                                                   int matOff, int sub, int nbkt,
                                                   unsigned* __restrict__ part) {
    extern __shared__ int cur[];   // nbkt ints
    const int b = blockIdx.x, tid = threadIdx.x;
    for (int j = tid; j < nbkt; j += 256)
        cur[j] = mat[matOff + j * NB + b] - sub;
    __syncthreads();
    const int base = b * CHUNK;
    for (int i = tid; i < CHUNK; i += 256) {
        const int k = key[base + i];
        const int p = atomicAdd(&cur[k >> 6], 1);
        part[p] = (unsigned)val[base + i] | ((unsigned)(k & 63) << 17);
    }
}

// ---------------------------------------------------------------------------
// Per-bucket counting sort -> CSR offsets + ordered adj
// ---------------------------------------------------------------------------
__global__ __launch_bounds__(256) void k_buildcsr(const unsigned* __restrict__ part,
                                                  const int* __restrict__ mat,
                                                  int matOff, int sub,
                                                  int* __restrict__ offOut,
                                                  int* __restrict__ adj,
                                                  int nMajor) {
    const int b = blockIdx.x;
    const int tid = threadIdx.x;
    const int base = mat[matOff + b * NB] - sub;
    const int end  = (b == (int)gridDim.x - 1) ? NNZ : (mat[matOff + (b + 1) * NB] - sub);
    const int nb = end - base;
    const int k0 = b << 6;

    __shared__ int hist[64], cur[64];
    if (tid < 64) hist[tid] = 0;
    __syncthreads();

    for (int i = tid; i < nb; i += 256)
        atomicAdd(&hist[(part[base + i] >> 17) & 63], 1);
    __syncthreads();

    if (tid == 0) {
        int s = 0;
        for (int k = 0; k < 64; ++k) {
            int h = hist[k];
            hist[k] = s;
            cur[k] = s;
            s += h;
        }
    }
    __syncthreads();

    const int lim = min(64, nMajor - k0);
    if (tid < lim) offOut[k0 + tid] = base + hist[tid];
    if (b == 0 && tid == 0) offOut[nMajor] = NNZ;

    for (int i = tid; i < nb; i += 256) {
        const unsigned u = part[base + i];
        const int lk = (u >> 17) & 63;
        adj[base + atomicAdd(&cur[lk], 1)] = (int)(u & 0x1FFFFu);
    }
}

// ---------------------------------------------------------------------------
// Stage 1 (pull): one wave per edge; lane = channel; 8x unrolled.
// ---------------------------------------------------------------------------
__global__ __launch_bounds__(256) void k_gatherE(const float* __restrict__ Xp,
                                                 const int* __restrict__ offE,
                                                 const int* __restrict__ adj,
                                                 const float* __restrict__ degE,
                                                 const float* __restrict__ Wdiag,
                                                 float* __restrict__ Xe) {
    const int wave = (blockIdx.x * 256 + threadIdx.x) >> 6;
    const int lane = threadIdx.x & 63;
    if (wave >= NE) return;
    const int b = offE[wave];
    const int e = offE[wave + 1];
    float acc = 0.0f;
    for (int base = b; base < e; base += 64) {
        const int m = min(64, e - base);
        const int vi = (base + lane < e) ? adj[base + lane] : 0;
        int t = 0;
        for (; t + 8 <= m; t += 8) {
            const int i0 = __shfl(vi, t + 0, 64);
            const int i1 = __shfl(vi, t + 1, 64);
            const int i2 = __shfl(vi, t + 2, 64);
            const int i3 = __shfl(vi, t + 3, 64);
            const int i4 = __shfl(vi, t + 4, 64);
            const int i5 = __shfl(vi, t + 5, 64);
            const int i6 = __shfl(vi, t + 6, 64);
            const int i7 = __shfl(vi, t + 7, 64);
            const float a0 = Xp[(size_t)i0 * KOUT + lane];
            const float a1 = Xp[(size_t)i1 * KOUT + lane];
            const float a2 = Xp[(size_t)i2 * KOUT + lane];
            const float a3 = Xp[(size_t)i3 * KOUT + lane];
            const float a4 = Xp[(size_t)i4 * KOUT + lane];
            const float a5 = Xp[(size_t)i5 * KOUT + lane];
            const float a6 = Xp[(size_t)i6 * KOUT + lane];
            const float a7 = Xp[(size_t)i7 * KOUT + lane];
            acc += ((a0 + a1) + (a2 + a3)) + ((a4 + a5) + (a6 + a7));
        }
        for (; t < m; ++t) {
            const int v = __shfl(vi, t, 64);
            acc += Xp[(size_t)v * KOUT + lane];
        }
    }
    Xe[(size_t)wave * KOUT + lane] = acc * (degE[wave] * Wdiag[wave]);
}

// ---------------------------------------------------------------------------
// Stage 2 (pull): one wave per vertex.
// ---------------------------------------------------------------------------
__global__ __launch_bounds__(256) void k_gatherV(const float* __restrict__ Xe,
                                                 const int* __restrict__ offV,
                                                 const int* __restrict__ adj,
                                                 const float* __restrict__ degV,
                                                 float* __restrict__ out) {
    const int wave = (blockIdx.x * 256 + threadIdx.x) >> 6;
    const int lane = threadIdx.x & 63;
    if (wave >= NV) return;
    const int b = offV[wave];
    const int e = offV[wave + 1];
    float acc = 0.0f;
    for (int base = b; base < e; base += 64) {
        const int m = min(64, e - base);
        const int ei = (base + lane < e) ? adj[base + lane] : 0;
        int t = 0;
        for (; t + 8 <= m; t += 8) {
            const int i0 = __shfl(ei, t + 0, 64);
            const int i1 = __shfl(ei, t + 1, 64);
            const int i2 = __shfl(ei, t + 2, 64);
            const int i3 = __shfl(ei, t + 3, 64);
            const int i4 = __shfl(ei, t + 4, 64);
            const int i5 = __shfl(ei, t + 5, 64);
            const int i6 = __shfl(ei, t + 6, 64);
            const int i7 = __shfl(ei, t + 7, 64);
            const float a0 = Xe[(size_t)i0 * KOUT + lane];
            const float a1 = Xe[(size_t)i1 * KOUT + lane];
            const float a2 = Xe[(size_t)i2 * KOUT + lane];
            const float a3 = Xe[(size_t)i3 * KOUT + lane];
            const float a4 = Xe[(size_t)i4 * KOUT + lane];
            const float a5 = Xe[(size_t)i5 * KOUT + lane];
            const float a6 = Xe[(size_t)i6 * KOUT + lane];
            const float a7 = Xe[(size_t)i7 * KOUT + lane];
            acc += ((a0 + a1) + (a2 + a3)) + ((a4 + a5) + (a6 + a7));
        }
        for (; t < m; ++t) {
            const int ee = __shfl(ei, t, 64);
            acc += Xe[(size_t)ee * KOUT + lane];
        }
    }
    out[(size_t)wave * KOUT + lane] = acc * degV[wave];
}

extern "C" void kernel_launch(void* const* d_in, const int* in_sizes, int n_in,
                              void* d_out, int out_size, void* d_ws, size_t ws_size,
                              hipStream_t stream) {
    const float* X     = (const float*)d_in[0];
    const float* W     = (const float*)d_in[1];
    const float* degE  = (const float*)d_in[2];
    const float* degV  = (const float*)d_in[3];
    const float* Wdiag = (const float*)d_in[4];
    const int*   v_idx = (const int*)d_in[5];
    const int*   e_idx = (const int*)d_in[6];
    float* out = (float*)d_out;

    // Workspace (~68 MB). part/adj reused for E then V phases (stream-ordered).
    float*    Xp   = (float*)d_ws;                       // NV*KOUT floats
    float*    Xe   = Xp + (size_t)NV * KOUT;             // NE*KOUT floats
    int*      adj  = (int*)(Xe + (size_t)NE * KOUT);     // NNZ
    unsigned* part = (unsigned*)(adj + NNZ);             // NNZ
    int*      offE = (int*)(part + NNZ);                 // NE+1
    int*      offV = offE + (NE + 1);                    // NV+1
    int*      mat  = offV + (NV + 1);                    // LSCAN
    int*      bsum = mat + LSCAN;                        // NBLK_SCAN

    k_project<<<NV / 32, 256, 0, stream>>>(X, W, Xp);    // 3125 blocks, no tail

    // Contention-free bucket counts + parallel exclusive scan
    k_hist<<<NB, 256, 0, stream>>>(v_idx, e_idx, mat);
    k_scan1<<<NBLK_SCAN, 1024, 0, stream>>>(mat, bsum);
    k_scan2<<<1, 1024, 0, stream>>>(bsum);
    k_scan3<<<NBLK_SCAN, 1024, 0, stream>>>(mat, bsum);

    // ---- Edge side: partition -> CSR -> gather
    k_partition<<<NB, 256, NBE * sizeof(int), stream>>>(e_idx, v_idx, mat, 0, 0, NBE, part);
    k_buildcsr<<<NBE, 256, 0, stream>>>(part, mat, 0, 0, offE, adj, NE);
    k_gatherE<<<(NE * 64) / 256, 256, 0, stream>>>(Xp, offE, adj, degE, Wdiag, Xe);

    // ---- Vertex side: partition -> CSR -> gather (reuses part/adj)
    k_partition<<<NB, 256, NBV * sizeof(int), stream>>>(v_idx, e_idx, mat, NBE * NB, NNZ, NBV, part);
    k_buildcsr<<<NBV, 256, 0, stream>>>(part, mat, NBE * NB, NNZ, offV, adj, NV);
    k_gatherV<<<(NV * 64) / 256, 256, 0, stream>>>(Xe, offV, adj, degV, out);
}